// Round 10
// baseline (268.329 us; speedup 1.0000x reference)
//
#include <hip/hip_runtime.h>

// ---------------- problem constants ----------------
#define T_ 8
#define N_ 256
#define C_ 1024
#define H_ 16
#define D_ 64
#define U_ 2056      // fused tokens per batch = T*(N+1)
#define UPAD_ 2112   // 33*64
#define MROWS_ 4112  // B*U
#define MPAD_ 4224   // 33*128
#define IMG_OUT_ELEMS 4194304  // 2*8*256*1024

typedef __attribute__((ext_vector_type(4))) float f32x4;
typedef __attribute__((ext_vector_type(8))) short s16x8;
typedef __attribute__((ext_vector_type(4))) short s16x4;

__device__ __forceinline__ short f2bf(float f) {
  union { float f; unsigned u; } a; a.f = f;
  unsigned u = a.u;
  return (short)((u + 0x7fffu + ((u >> 16) & 1u)) >> 16);
}

__device__ __forceinline__ float b2f(short s) {
  union { unsigned u; float f; } a;
  a.u = ((unsigned)(unsigned short)s) << 16;
  return a.f;
}

// bare v_exp_f32 (2^x). q is pre-scaled by log2(e) so softmax runs in exp2 domain.
__device__ __forceinline__ float exp2a(float x) {
  float r; asm("v_exp_f32 %0, %1" : "=v"(r) : "v"(x)); return r;
}

__device__ __forceinline__ unsigned cvt_pk_bf16(float lo, float hi) {
  unsigned r; asm("v_cvt_pk_bf16_f32 %0, %1, %2" : "=v"(r) : "v"(lo), "v"(hi)); return r;
}

#define ASYNC_COPY16(gp, lp)                                                   \
  __builtin_amdgcn_global_load_lds((const __attribute__((address_space(1))) void*)(gp), \
                                   (__attribute__((address_space(3))) void*)(lp), 16, 0, 0)

// ---------------- workspace offsets (bytes) ----------------
constexpr size_t OFF_XB     = 0;                         // 4224*1024*2
constexpr size_t OFF_WQKVT  = OFF_XB + 8650752;          // 3072*1024*2
constexpr size_t OFF_WPROJT = OFF_WQKVT + 6291456;       // 1024*1024*2
constexpr size_t OFF_Q      = OFF_WPROJT + 2097152;      // 32*2056*64*2
constexpr size_t OFF_K      = OFF_Q + 8421376;           // 32*2112*64*2
constexpr size_t OFF_V      = OFF_K + 8650752;           // 32*2112*64*2
constexpr size_t OFF_VT     = OFF_V + 8650752;           // 32*64*2112*2
constexpr size_t OFF_X      = OFF_VT + 8650752;          // 4224*1024*2
// total ~60 MB

// ---------------- fused prep: pack X + both weight transposes ----------------
__global__ __launch_bounds__(256) void prep_kernel(const float* __restrict__ img,
                                                   const float* __restrict__ cam,
                                                   short* __restrict__ Xb,
                                                   const float* __restrict__ wqkv,
                                                   short* __restrict__ Wqkvt,
                                                   const float* __restrict__ wproj,
                                                   short* __restrict__ Wprojt) {
  __shared__ float tile[32][33];
  const int bid = blockIdx.x;
  if (bid < 4112) {
    int gt = bid * 256 + threadIdx.x;
    int e = gt << 2;                      // 4 floats per thread, exact cover of 4112*1024
    int row = e >> 10, col = e & 1023;
    int b = row / U_, u = row % U_, t = u / 257, jj = u % 257;
    const float* src = jj ? (img + ((size_t)((b * 8 + t) * 256 + (jj - 1)) << 10))
                          : (cam + ((size_t)(b * 8 + t) << 10));
    float4 f = *(const float4*)(src + col);
    s16x4 o;
    o[0] = f2bf(f.x); o[1] = f2bf(f.y); o[2] = f2bf(f.z); o[3] = f2bf(f.w);
    *(s16x4*)(Xb + ((size_t)row << 10) + col) = o;
    return;
  }
  const float* in; short* out; int Cc, bx, by;
  if (bid < 4112 + 3072) {
    int i = bid - 4112; bx = i % 96; by = i / 96; in = wqkv; out = Wqkvt; Cc = 3072;
  } else {
    int i = bid - 7184; bx = i % 32; by = i / 32; in = wproj; out = Wprojt; Cc = 1024;
  }
  constexpr int R = 1024;
  int tx = threadIdx.x & 31, ty = threadIdx.x >> 5;
  int col0 = bx << 5, row0 = by << 5;
#pragma unroll
  for (int i = 0; i < 4; i++) {
    int r = ty + i * 8;
    tile[r][tx] = in[(size_t)(row0 + r) * Cc + col0 + tx];
  }
  __syncthreads();
#pragma unroll
  for (int i = 0; i < 4; i++) {
    int r = ty + i * 8;
    out[(size_t)(col0 + r) * R + row0 + tx] = f2bf(tile[tx][r]);
  }
}

// ---------------- 64x128 bf16 GEMM, Bt is [N][K] row-major ----------------
// Double-buffered LDS; prefetch-after-barrier; T2 granule swizzle.
// EPI 0: QKV+RoPE.  EPI 1: proj+bias.
template <int EPI>
__global__ __launch_bounds__(256) void gemm_kernel(
    const short* __restrict__ A, const short* __restrict__ Bt,
    const float* __restrict__ cosi, const float* __restrict__ sini,
    const float* __restrict__ cosc, const float* __restrict__ sinc,
    short* __restrict__ qb, short* __restrict__ kb, short* __restrict__ vb,
    const float* __restrict__ bias, float* __restrict__ outp) {
  constexpr int K = 1024;
  __shared__ __align__(16) short As[2][64 * 32];
  __shared__ __align__(16) short Bs[2][128 * 32];
  const int tid = threadIdx.x, w = tid >> 6, lane = tid & 63;
  const int l16 = lane & 15, quad = lane >> 4;

  int bn, bm;
  {
    const int flat = blockIdx.x;
    const int xcd = flat & 7, idx = flat >> 3;
    if constexpr (EPI == 0) { bn = xcd * 3 + idx / 66; bm = idx % 66; }   // 1584 blocks
    else                    { bn = xcd;                bm = idx;       }  // 528 blocks
  }

  const f32x4 zero = {0.f, 0.f, 0.f, 0.f};
  f32x4 acc[2][4];
#pragma unroll
  for (int i = 0; i < 2; i++)
#pragma unroll
    for (int j = 0; j < 4; j++) acc[i][j] = zero;

  const int mb = (w >> 1) << 5, nb = (w & 1) << 6;   // wave tile 32x64

  const int srow = tid >> 2;                 // 0..63
  const int cseg = (((tid & 3) ^ (srow & 3)) << 3);
  const short* gA = A + (size_t)(bm * 64 + srow) * K + cseg;
  const short* gB = Bt + (size_t)(bn * 128 + srow) * K + cseg;
  const int lo = tid * 16;                   // bytes (linear LDS dest)

#define STAGE(buf, kb0)                                                        \
  do {                                                                         \
    ASYNC_COPY16(gA + (kb0), (char*)As[buf] + lo);                             \
    ASYNC_COPY16(gB + (kb0), (char*)Bs[buf] + lo);                             \
    ASYNC_COPY16(gB + (size_t)64 * K + (kb0), (char*)Bs[buf] + lo + 4096);     \
  } while (0)

  STAGE(0, 0);
  int cur = 0;
  const int gsw = (quad ^ (l16 & 3)) << 3;
  for (int kb0 = 0; kb0 < K; kb0 += 32) {
    __syncthreads();                 // drains vmcnt -> buf[cur] ready
    if (kb0 + 32 < K) STAGE(cur ^ 1, kb0 + 32);   // prefetch flies under compute
    s16x8 af[2], bf[4];
#pragma unroll
    for (int mi = 0; mi < 2; mi++)
      af[mi] = *(const s16x8*)&As[cur][(mb + mi * 16 + l16) * 32 + gsw];
#pragma unroll
    for (int ni = 0; ni < 4; ni++)
      bf[ni] = *(const s16x8*)&Bs[cur][(nb + ni * 16 + l16) * 32 + gsw];
#pragma unroll
    for (int mi = 0; mi < 2; mi++)
#pragma unroll
      for (int ni = 0; ni < 4; ni++)
        acc[mi][ni] = __builtin_amdgcn_mfma_f32_16x16x32_bf16(af[mi], bf[ni], acc[mi][ni], 0, 0, 0);
    cur ^= 1;
  }
#undef STAGE

  if constexpr (EPI == 0) {
    const int cbase = bn * 128 + nb;          // wave-uniform
    const int which = cbase >> 10;            // 0=q 1=k 2=v
    const int hh = (cbase & 1023) >> 6;       // head, wave-uniform
#pragma unroll
    for (int mi = 0; mi < 2; mi++) {
#pragma unroll
      for (int reg = 0; reg < 4; reg++) {
        const int R = bm * 64 + mb + mi * 16 + quad * 4 + reg;
        if (R < MROWS_) {
          const int b = (R >= U_) ? 1 : 0;
          const int u = R - b * U_;
          const int t = (u - (u >> 8)) >> 8;  // u/257 for u<2056
          const int jj = u - ((t << 8) + t);
          const int bh = b * 16 + hh;
          if (which == 2) {
#pragma unroll
            for (int ni = 0; ni < 4; ni++)
              vb[((size_t)bh * UPAD_ + u) * 64 + ni * 16 + l16] = f2bf(acc[mi][ni][reg]);
          } else {
            const float *ct, *st; int pos;
            if (jj == 0) { ct = cosc; st = sinc; pos = t; }
            else         { ct = cosi; st = sini; pos = u - t - 1; }
#pragma unroll
            for (int ni = 0; ni < 4; ni++) {
              const int d = ni * 16 + l16;
              const float val = acc[mi][ni][reg];
              const float partner = __shfl_xor(val, 1, 64);  // d^1 neighbor, same row
              const float cv = ct[pos * 64 + d], sv = st[pos * 64 + d];
              float o = val * cv + ((d & 1) ? partner : -partner) * sv;
              if (which == 0) {
                o *= 0.18033688f;  // fold 1/sqrt(64) * log2(e) into q
                qb[((size_t)bh * U_ + u) * 64 + d] = f2bf(o);
              } else {
                kb[((size_t)bh * UPAD_ + u) * 64 + d] = f2bf(o);
              }
            }
          }
        }
      }
    }
  } else {
    const int cbase = bn * 128 + nb;
#pragma unroll
    for (int mi = 0; mi < 2; mi++) {
#pragma unroll
      for (int reg = 0; reg < 4; reg++) {
        const int R = bm * 64 + mb + mi * 16 + quad * 4 + reg;
        if (R < MROWS_) {
          const int b = (R >= U_) ? 1 : 0;
          const int u = R - b * U_;
          const int t = (u - (u >> 8)) >> 8;
          const int jj = u - ((t << 8) + t);
          size_t rowoff;
          if (jj) rowoff = (size_t)((b * 8 + t) * 256 + jj - 1) * 1024;
          else    rowoff = IMG_OUT_ELEMS + (size_t)(b * 8 + t) * 1024;
#pragma unroll
          for (int ni = 0; ni < 4; ni++) {
            const int Cg = cbase + ni * 16 + l16;
            outp[rowoff + Cg] = acc[mi][ni][reg] + bias[Cg];
          }
        }
      }
    }
  }
}

// ---------------- fused flash attention (img queries only) ----------------
// 512 blocks of 128 q-rows (4 waves x 32 q-rows as two 16-col groups A/B).
// Every shared K-frag / V-frag ds_read_b128 feeds TWO MFMAs (A and B) ->
// LDS read traffic per q-row HALVES (attn was ~80% LDS-BW-bound).
// XCD decode: each XCD owns 4 bh (K/V L2-resident); K/V HBM re-reads halve.
__global__ __launch_bounds__(256) void attn_kernel(const short* __restrict__ q,
                                                   const short* __restrict__ k,
                                                   const short* __restrict__ vt,
                                                   short* __restrict__ x) {
  __shared__ __align__(16) short Kt[64 * 64];       // [kv][d] XOR-swizzled
  __shared__ __align__(16) short Vt[64 * 64];       // [d][kv] XOR-swizzled
  __shared__ __align__(16) short Pt[4 * 32 * 72];   // per-wave [q(32)][kv]
  const int tid = threadIdx.x, w = tid >> 6, lane = tid & 63;
  const int l16 = lane & 15, quad = lane >> 4;
  const int flat = blockIdx.x;
  const int slot = flat >> 3;
  const int bh = ((flat & 7) << 2) + (slot >> 4);
  const int qt = slot & 15;                          // 16 tiles of 128 q-rows
  const int b = bh >> 4, h = bh & 15;

  // q rows: global img row g -> fused u = g + (g>>8) + 1
  const int gA = qt * 128 + w * 16 + l16;
  const int gB = gA + 64;
  const int uA = gA + (gA >> 8) + 1;
  const int uB = gB + (gB >> 8) + 1;
  const short* qpA = q + ((size_t)bh * U_ + uA) * 64;
  const short* qpB = q + ((size_t)bh * U_ + uB) * 64;
  const s16x8 aq0A = *(const s16x8*)(qpA + quad * 8);
  const s16x8 aq1A = *(const s16x8*)(qpA + 32 + quad * 8);
  const s16x8 aq0B = *(const s16x8*)(qpB + quad * 8);
  const s16x8 aq1B = *(const s16x8*)(qpB + 32 + quad * 8);

  // reg-staging geometry: lane stages rows sr and sr+32, 16B granule c8.
  const int sr = w * 8 + (lane >> 3);              // 0..31
  const int c8 = lane & 7;
  const short* kg = k + ((size_t)bh * UPAD_ + sr) * 64 + (c8 << 3);
  const short* vg = vt + ((size_t)bh * 64 + sr) * UPAD_ + (c8 << 3);
  const int swz = ((c8 ^ (sr & 7)) << 3);          // (sr+32)&7 == sr&7
  short* const wk0 = &Kt[sr * 64 + swz];
  short* const wk1 = &Kt[(sr + 32) * 64 + swz];
  short* const wv0 = &Vt[sr * 64 + swz];
  short* const wv1 = &Vt[(sr + 32) * 64 + swz];

  // swizzled LDS read columns (shorts); row = ni*16+l16 -> row&7 = l16&7
  const int cK0 = (quad * 8) ^ ((l16 & 7) << 3);
  const int cK1 = (32 + quad * 8) ^ ((l16 & 7) << 3);
  short* const pwA = Pt + (w * 32 + l16) * 72;
  short* const pwB = pwA + 16 * 72;

  const f32x4 zero = {0.f, 0.f, 0.f, 0.f};
  const s16x8 vones = {16256, 16256, 16256, 16256, 16256, 16256, 16256, 16256}; // bf16 1.0
  float mA = -3e38f, mB = -3e38f;
  f32x4 lA = zero, lB = zero;
  f32x4 oA[4], oB[4];
#pragma unroll
  for (int r = 0; r < 4; r++) { oA[r] = zero; oB[r] = zero; }

  // prologue: stage tile 0 into regs
  s16x8 rk0 = *(const s16x8*)(kg);
  s16x8 rk1 = *(const s16x8*)(kg + 2048);
  s16x8 rv0 = *(const s16x8*)(vg);
  s16x8 rv1 = *(const s16x8*)(vg + 32 * UPAD_);
  kg += 64 * 64;
  vg += 64;

  for (int kv0 = 0; kv0 < U_; kv0 += 64) {
    __syncthreads();                 // prev tile's LDS reads complete
    *(s16x8*)wk0 = rk0;
    *(s16x8*)wk1 = rk1;
    *(s16x8*)wv0 = rv0;
    *(s16x8*)wv1 = rv1;
    __syncthreads();                 // LDS ready
    if (kv0 + 64 < U_) {             // issue next-tile loads; hide under compute
      rk0 = *(const s16x8*)(kg);
      rk1 = *(const s16x8*)(kg + 2048);
      rv0 = *(const s16x8*)(vg);
      rv1 = *(const s16x8*)(vg + 32 * UPAD_);
      kg += 64 * 64;
      vg += 64;
    }

    // S^T = K Q^T for both q-groups; each K-frag read feeds 2 MFMAs
    f32x4 sTA[4], sTB[4];
    __builtin_amdgcn_s_setprio(1);
#pragma unroll
    for (int ni = 0; ni < 4; ni++) {
      const s16x8 b0 = *(const s16x8*)&Kt[(ni * 16 + l16) * 64 + cK0];
      const s16x8 b1 = *(const s16x8*)&Kt[(ni * 16 + l16) * 64 + cK1];
      f32x4 zA = __builtin_amdgcn_mfma_f32_16x16x32_bf16(b0, aq0A, zero, 0, 0, 0);
      sTA[ni] = __builtin_amdgcn_mfma_f32_16x16x32_bf16(b1, aq1A, zA, 0, 0, 0);
      f32x4 zB = __builtin_amdgcn_mfma_f32_16x16x32_bf16(b0, aq0B, zero, 0, 0, 0);
      sTB[ni] = __builtin_amdgcn_mfma_f32_16x16x32_bf16(b1, aq1B, zB, 0, 0, 0);
    }
    __builtin_amdgcn_s_setprio(0);

    // tail tile: real kv are 2048..2055 -> kv_local = ni*16+quad*4+reg < 8
    if (kv0 == 2048) {
#pragma unroll
      for (int ni = 0; ni < 4; ni++) {
        if (ni > 0 || quad >= 2) {
#pragma unroll
          for (int r2 = 0; r2 < 4; r2++) { sTA[ni][r2] = -1e30f; sTB[ni][r2] = -1e30f; }
        }
      }
    }

    // ---- softmax group A (in-lane; lane owns q-row l16) ----
    {
      float t0 = fmaxf(fmaxf(sTA[0][0], sTA[0][1]), sTA[0][2]);
      float t1 = fmaxf(fmaxf(sTA[0][3], sTA[1][0]), sTA[1][1]);
      float t2 = fmaxf(fmaxf(sTA[1][2], sTA[1][3]), sTA[2][0]);
      float t3 = fmaxf(fmaxf(sTA[2][1], sTA[2][2]), sTA[2][3]);
      float t4 = fmaxf(fmaxf(sTA[3][0], sTA[3][1]), sTA[3][2]);
      float mx = fmaxf(fmaxf(fmaxf(t0, t1), t2), fmaxf(fmaxf(t3, t4), sTA[3][3]));
      mx = fmaxf(mx, __shfl_xor(mx, 16, 64));
      mx = fmaxf(mx, __shfl_xor(mx, 32, 64));
      if (__any(mx > mA + 8.f)) {          // T13 defer-max
        const float mnew = fmaxf(mA, mx);
        const float al = exp2a(mA - mnew);
        mA = mnew;
        float aR[4];
#pragma unroll
        for (int reg = 0; reg < 4; reg++) aR[reg] = __shfl(al, quad * 4 + reg, 64);
#pragma unroll
        for (int ni = 0; ni < 4; ni++)
#pragma unroll
          for (int reg = 0; reg < 4; reg++) oA[ni][reg] *= aR[reg];
#pragma unroll
        for (int reg = 0; reg < 4; reg++) lA[reg] *= aR[reg];
      }
#pragma unroll
      for (int ni = 0; ni < 4; ni++)
#pragma unroll
        for (int reg = 0; reg < 4; reg++) sTA[ni][reg] = exp2a(sTA[ni][reg] - mA);
#pragma unroll
      for (int ni = 0; ni < 4; ni++) {
        uint2 pk;
        pk.x = cvt_pk_bf16(sTA[ni][0], sTA[ni][1]);
        pk.y = cvt_pk_bf16(sTA[ni][2], sTA[ni][3]);
        *(uint2*)&pwA[ni * 16 + quad * 4] = pk;
      }
    }
    // ---- softmax group B ----
    {
      float t0 = fmaxf(fmaxf(sTB[0][0], sTB[0][1]), sTB[0][2]);
      float t1 = fmaxf(fmaxf(sTB[0][3], sTB[1][0]), sTB[1][1]);
      float t2 = fmaxf(fmaxf(sTB[1][2], sTB[1][3]), sTB[2][0]);
      float t3 = fmaxf(fmaxf(sTB[2][1], sTB[2][2]), sTB[2][3]);
      float t4 = fmaxf(fmaxf(sTB[3][0], sTB[3][1]), sTB[3][2]);
      float mx = fmaxf(fmaxf(fmaxf(t0, t1), t2), fmaxf(fmaxf(t3, t4), sTB[3][3]));
      mx = fmaxf(mx, __shfl_xor(mx, 16, 64));
      mx = fmaxf(mx, __shfl_xor(mx, 32, 64));
      if (__any(mx > mB + 8.f)) {
        const float mnew = fmaxf(mB, mx);
        const float al = exp2a(mB - mnew);
        mB = mnew;
        float aR[4];
#pragma unroll
        for (int reg = 0; reg < 4; reg++) aR[reg] = __shfl(al, quad * 4 + reg, 64);
#pragma unroll
        for (int ni = 0; ni < 4; ni++)
#pragma unroll
          for (int reg = 0; reg < 4; reg++) oB[ni][reg] *= aR[reg];
#pragma unroll
        for (int reg = 0; reg < 4; reg++) lB[reg] *= aR[reg];
      }
#pragma unroll
      for (int ni = 0; ni < 4; ni++)
#pragma unroll
        for (int reg = 0; reg < 4; reg++) sTB[ni][reg] = exp2a(sTB[ni][reg] - mB);
#pragma unroll
      for (int ni = 0; ni < 4; ni++) {
        uint2 pk;
        pk.x = cvt_pk_bf16(sTB[ni][0], sTB[ni][1]);
        pk.y = cvt_pk_bf16(sTB[ni][2], sTB[ni][3]);
        *(uint2*)&pwB[ni * 16 + quad * 4] = pk;
      }
    }

    // O += P V for both groups; each V-frag read feeds 2 MFMAs.
    const s16x8 apA0 = *(const s16x8*)&pwA[quad * 8];
    const s16x8 apA1 = *(const s16x8*)&pwA[32 + quad * 8];
    const s16x8 apB0 = *(const s16x8*)&pwB[quad * 8];
    const s16x8 apB1 = *(const s16x8*)&pwB[32 + quad * 8];
    __builtin_amdgcn_s_setprio(1);
    lA = __builtin_amdgcn_mfma_f32_16x16x32_bf16(apA0, vones, lA, 0, 0, 0);
    lB = __builtin_amdgcn_mfma_f32_16x16x32_bf16(apB0, vones, lB, 0, 0, 0);
#pragma unroll
    for (int ni = 0; ni < 4; ni++) {
      const s16x8 bv = *(const s16x8*)&Vt[(ni * 16 + l16) * 64 + cK0];
      oA[ni] = __builtin_amdgcn_mfma_f32_16x16x32_bf16(apA0, bv, oA[ni], 0, 0, 0);
      oB[ni] = __builtin_amdgcn_mfma_f32_16x16x32_bf16(apB0, bv, oB[ni], 0, 0, 0);
    }
    lA = __builtin_amdgcn_mfma_f32_16x16x32_bf16(apA1, vones, lA, 0, 0, 0);
    lB = __builtin_amdgcn_mfma_f32_16x16x32_bf16(apB1, vones, lB, 0, 0, 0);
#pragma unroll
    for (int ni = 0; ni < 4; ni++) {
      const s16x8 bv = *(const s16x8*)&Vt[(ni * 16 + l16) * 64 + cK1];
      oA[ni] = __builtin_amdgcn_mfma_f32_16x16x32_bf16(apA1, bv, oA[ni], 0, 0, 0);
      oB[ni] = __builtin_amdgcn_mfma_f32_16x16x32_bf16(apB1, bv, oB[ni], 0, 0, 0);
    }
    __builtin_amdgcn_s_setprio(0);
  }

  // l in o_acc layout (row = quad*4+reg); all 16 cols identical
  f32x4 liA, liB;
#pragma unroll
  for (int reg = 0; reg < 4; reg++) { liA[reg] = 1.f / lA[reg]; liB[reg] = 1.f / lB[reg]; }

  // write x[b*2056+u][h*64+d] bf16 (o row = quad*4+reg, col = ni*16+l16)
#pragma unroll
  for (int reg = 0; reg < 4; reg++) {
    const int goA = qt * 128 + w * 16 + quad * 4 + reg;
    const int uoA = goA + (goA >> 8) + 1;
    const int goB = goA + 64;
    const int uoB = goB + (goB >> 8) + 1;
#pragma unroll
    for (int ni = 0; ni < 4; ni++) {
      x[((size_t)(b * U_ + uoA)) * 1024 + h * 64 + ni * 16 + l16] =
          f2bf(oA[ni][reg] * liA[reg]);
      x[((size_t)(b * U_ + uoB)) * 1024 + h * 64 + ni * 16 + l16] =
          f2bf(oB[ni][reg] * liB[reg]);
    }
  }
}

// ---------------- fused vt transpose + cam-query attention ----------------
// blocks 0..1055: bf16 v[bh][2112][64] -> vt[bh][64][2112] (zero pad rows)
// blocks 1056..1311: cam attention; decode puts all 8 t-blocks of a bh on the
// SAME XCD (block_id%8 == bh&7) so K/V re-reads hit that XCD's L2.
__global__ __launch_bounds__(256) void vtcam_kernel(const short* __restrict__ v,
                                                    short* __restrict__ vt,
                                                    const short* __restrict__ q,
                                                    const short* __restrict__ k,
                                                    short* __restrict__ x) {
  __shared__ __align__(16) char smem[16448];
  const int bid = blockIdx.x;
  const int tid = threadIdx.x;
  if (bid < 1056) {
    short (*t2)[65] = (short(*)[65])smem;          // 64*65*2 = 8320 B
    int kt = bid % 33, bh = bid / 33;
#pragma unroll
    for (int i = 0; i < 16; i++) {
      int e = tid + i * 256; int r = e >> 6, c = e & 63;
      short vv = v[((size_t)bh * UPAD_ + kt * 64 + r) * 64 + c];
      t2[r][c] = (kt * 64 + r < U_) ? vv : (short)0;
    }
    __syncthreads();
#pragma unroll
    for (int i = 0; i < 16; i++) {
      int e = tid + i * 256; int d = e >> 6, c = e & 63;
      vt[((size_t)bh * 64 + d) * UPAD_ + kt * 64 + c] = t2[c][d];
    }
    return;
  }
  float* sb = (float*)smem;                        // 2056 floats
  float* red = sb + U_;                            // 8 floats
  float (*obuf)[64] = (float(*)[64])(red + 8);     // 32*64 floats
  const int i0 = bid - 1056;                       // XCD of this block = i0 & 7
  const int bh = (i0 & 7) + ((i0 >> 6) << 3);      // bh&7 == i0&7 -> same XCD per bh
  const int t = (i0 >> 3) & 7;
  const int b = bh >> 4, h = bh & 15;
  const int L = (t + 1) * 257;
  const int lane = tid & 63, w = tid >> 6;
  const int u_q = t * 257;

  float qf[64];
  {
    const short* qpp = q + ((size_t)bh * U_ + u_q) * 64;
#pragma unroll
    for (int i = 0; i < 8; i++) {
      const s16x8 qv = *(const s16x8*)(qpp + i * 8);
#pragma unroll
      for (int j = 0; j < 8; j++) qf[i * 8 + j] = b2f(qv[j]);
    }
  }

  float lm = -3e38f;
  for (int kv = tid; kv < L; kv += 256) {
    const short* kp = k + ((size_t)bh * UPAD_ + kv) * 64;
    float s = 0.f;
#pragma unroll
    for (int i = 0; i < 8; i++) {
      const s16x8 kvv = *(const s16x8*)(kp + i * 8);
#pragma unroll
      for (int j = 0; j < 8; j++) s += qf[i * 8 + j] * b2f(kvv[j]);
    }
    sb[kv] = s;
    lm = fmaxf(lm, s);
  }
#pragma unroll
  for (int d = 1; d < 64; d <<= 1) lm = fmaxf(lm, __shfl_xor(lm, d, 64));
  if (lane == 0) red[w] = lm;
  __syncthreads();
  const float m = fmaxf(fmaxf(red[0], red[1]), fmaxf(red[2], red[3]));

  float ls = 0.f;
  for (int kv = tid; kv < L; kv += 256) {
    const float p = exp2a(sb[kv] - m);
    sb[kv] = p;
    ls += p;
  }
#pragma unroll
  for (int d = 1; d < 64; d <<= 1) ls += __shfl_xor(ls, d, 64);
  if (lane == 0) red[4 + w] = ls;
  __syncthreads();
  const float linv = 1.f / (red[4] + red[5] + red[6] + red[7]);

  const int d0 = (tid & 7) << 3;
  const int slot = tid >> 3;
  float acc[8];
#pragma unroll
  for (int j = 0; j < 8; j++) acc[j] = 0.f;
  for (int kv = slot; kv < L; kv += 32) {
    const float p = sb[kv];
    const s16x8 vv = *(const s16x8*)(v + ((size_t)bh * UPAD_ + kv) * 64 + d0);
#pragma unroll
    for (int j = 0; j < 8; j++) acc[j] += p * b2f(vv[j]);
  }
#pragma unroll
  for (int j = 0; j < 8; j++) obuf[slot][d0 + j] = acc[j];
  __syncthreads();
  if (tid < 64) {
    float s = 0.f;
#pragma unroll
    for (int i = 0; i < 32; i++) s += obuf[i][tid];
    x[((size_t)(b * U_ + u_q)) * 1024 + h * 64 + tid] = f2bf(s * linv);
  }
}

// ---------------- launch ----------------
extern "C" void kernel_launch(void* const* d_in, const int* in_sizes, int n_in,
                              void* d_out, int out_size, void* d_ws, size_t ws_size,
                              hipStream_t stream) {
  const float* img   = (const float*)d_in[0];
  const float* cam   = (const float*)d_in[1];
  const float* wqkv  = (const float*)d_in[2];
  const float* wproj = (const float*)d_in[3];
  const float* bias  = (const float*)d_in[4];
  const float* cosi  = (const float*)d_in[5];
  const float* sini  = (const float*)d_in[6];
  const float* cosc  = (const float*)d_in[7];
  const float* sinc  = (const float*)d_in[8];
  float* outp = (float*)d_out;

  char* ws = (char*)d_ws;
  short* Xb     = (short*)(ws + OFF_XB);
  short* Wqkvt  = (short*)(ws + OFF_WQKVT);
  short* Wprojt = (short*)(ws + OFF_WPROJT);
  short* qb     = (short*)(ws + OFF_Q);
  short* kb     = (short*)(ws + OFF_K);
  short* vb     = (short*)(ws + OFF_V);
  short* vtb    = (short*)(ws + OFF_VT);
  short* xb     = (short*)(ws + OFF_X);

  prep_kernel<<<8208, 256, 0, stream>>>(img, cam, Xb, wqkv, Wqkvt, wproj, Wprojt);
  gemm_kernel<0><<<1584, 256, 0, stream>>>(Xb, Wqkvt, cosi, sini, cosc, sinc,
                                           qb, kb, vb, nullptr, nullptr);
  vtcam_kernel<<<1312, 256, 0, stream>>>(vb, vtb, qb, kb, xb);
  attn_kernel<<<512, 256, 0, stream>>>(qb, kb, vtb, xb);
  gemm_kernel<1><<<528, 256, 0, stream>>>(xb, Wprojt, nullptr, nullptr, nullptr, nullptr,
                                          nullptr, nullptr, nullptr, bias, outp);
}